// Round 13
// baseline (267.051 us; speedup 1.0000x reference)
//
#include <hip/hip_runtime.h>
#include <hip/hip_bf16.h>

typedef __hip_bfloat16 bf16;
using f32x4 = __attribute__((ext_vector_type(4))) float;
using f32x16 = __attribute__((ext_vector_type(16))) float;
using s16x8 = __attribute__((ext_vector_type(8))) short;

#define S_TOT 2274
#define S_PAD 2304
#define TTXT 226
#define DIMN 1920
#define NH 30
#define HD 64
#define NQKV 5760
#define QSCALE 0.1803368801f  // 0.125 * log2(e)
#define NSPLIT 3              // flash KV-split
#define SMAX 20.0f            // static softmax max (log2 domain); |score|<=23.1 hard bound

#define GLOAD_LDS16(g, l)                                                              \
  __builtin_amdgcn_global_load_lds((const __attribute__((address_space(1))) void*)(g), \
                                   (__attribute__((address_space(3))) void*)(l), 16, 0, 0)

// ---------------- merged prep: f32 -> bf16 for h, Wqkv, Wo (one launch) ----------------
__global__ void k_prep_all(const float* __restrict__ hid, const float* __restrict__ enc,
                           const float* __restrict__ Wq, const float* __restrict__ Wk,
                           const float* __restrict__ Wv, const float* __restrict__ Wo,
                           bf16* __restrict__ h_bf, bf16* __restrict__ wqkv,
                           bf16* __restrict__ wo_bf) {
  const long T1 = (long)S_PAD * DIMN;
  const long PER = (long)DIMN * DIMN;
  long i4 = ((long)blockIdx.x * blockDim.x + threadIdx.x) * 4;
  if (i4 >= T1 + 4 * PER) return;
  float4 v = make_float4(0.f, 0.f, 0.f, 0.f);
  bf16* dst;
  long di;
  if (i4 < T1) {
    int s = (int)(i4 / DIMN);
    if (s < TTXT)
      v = *reinterpret_cast<const float4*>(enc + i4);
    else if (s < S_TOT)
      v = *reinterpret_cast<const float4*>(hid + i4 - (long)TTXT * DIMN);
    dst = h_bf;
    di = i4;
  } else if (i4 < T1 + 3 * PER) {
    const long j = i4 - T1;
    const float* src = (j < PER) ? (Wq + j) : (j < 2 * PER) ? (Wk + j - PER) : (Wv + j - 2 * PER);
    v = *reinterpret_cast<const float4*>(src);
    dst = wqkv;
    di = j;
  } else {
    const long j = i4 - T1 - 3 * PER;
    v = *reinterpret_cast<const float4*>(Wo + j);
    dst = wo_bf;
    di = j;
  }
  union {
    bf16 b[4];
    short4 s4;
  } o;
  o.b[0] = __float2bfloat16(v.x);
  o.b[1] = __float2bfloat16(v.y);
  o.b[2] = __float2bfloat16(v.z);
  o.b[3] = __float2bfloat16(v.w);
  *reinterpret_cast<short4*>(dst + di) = o.s4;
}

// ==== fused QKV GEMM v9 (unchanged): 256x128, 8 waves, BK=32, tri-buffer 72KB ====
#define NKT32 60
#define QBUF 24576
__global__ __launch_bounds__(512, 4) void k_gemm_qkv9(
    const bf16* __restrict__ A, const bf16* __restrict__ B, const float* __restrict__ bq,
    const float* __restrict__ bk, const float* __restrict__ bv, const float* __restrict__ lqw,
    const float* __restrict__ lqb, const float* __restrict__ lkw, const float* __restrict__ lkb,
    const float* __restrict__ cosT, const float* __restrict__ sinT, bf16* __restrict__ qb,
    bf16* __restrict__ kbf, bf16* __restrict__ vt) {
  __shared__ __align__(16) char smem[3 * QBUF];
  const int tid = threadIdx.x;
  const int w = tid >> 6, lane = tid & 63;
  const int clo = lane & 15, lhi = lane >> 4;
  const int wr = w >> 1, wc = w & 1;
  const int m0 = blockIdx.y * 256, n0 = blockIdx.x * 128;

  const int u1 = 512 + tid;
  const long ga0 = (long)(m0 + (tid >> 2)) * DIMN + (((tid & 3) ^ ((tid >> 2) & 3)) * 8);
  const long ga1 = (long)(m0 + (u1 >> 2)) * DIMN + (((u1 & 3) ^ ((u1 >> 2) & 3)) * 8);
  const long gb0 = (long)(n0 + (tid >> 2)) * DIMN + (((tid & 3) ^ ((tid >> 2) & 3)) * 8);
  const int wbase = w * 1024;

  auto stage = [&](int b, int kt) {
    char* Ab = &smem[b * QBUF];
    char* Bb = Ab + 16384;
    const int ko = kt * 32;
    GLOAD_LDS16(A + ga0 + ko, Ab + wbase);
    GLOAD_LDS16(A + ga1 + ko, Ab + 8192 + wbase);
    GLOAD_LDS16(B + gb0 + ko, Bb + wbase);
  };

  auto rdf = [&](const char* base, int row) {
    return *reinterpret_cast<const s16x8*>(base + row * 64 + ((lhi ^ (row & 3)) * 16));
  };

  f32x4 acc[4][4] = {};

  stage(0, 0);
  stage(1, 1);
  for (int t = 0; t < NKT32; ++t) {
    if (t < NKT32 - 1)
      asm volatile("s_waitcnt vmcnt(3)" ::: "memory");
    else
      asm volatile("s_waitcnt vmcnt(0)" ::: "memory");
    __builtin_amdgcn_s_barrier();
    if (t + 2 < NKT32) stage((t + 2) % 3, t + 2);
    const char* Ab = &smem[(t % 3) * QBUF];
    const char* Bb = Ab + 16384;
    s16x8 af[4], bfr[4];
#pragma unroll
    for (int m = 0; m < 4; ++m) af[m] = rdf(Ab, wr * 64 + m * 16 + clo);
#pragma unroll
    for (int n = 0; n < 4; ++n) bfr[n] = rdf(Bb, wc * 64 + n * 16 + clo);
    __builtin_amdgcn_s_setprio(1);
#pragma unroll
    for (int m = 0; m < 4; ++m)
#pragma unroll
      for (int n = 0; n < 4; ++n)
        acc[m][n] = __builtin_amdgcn_mfma_f32_16x16x32_bf16(af[m], bfr[n], acc[m][n], 0, 0, 0);
    __builtin_amdgcn_s_setprio(0);
  }
  __syncthreads();

  const int gcol0 = n0 + wc * 64;
  const int sect = gcol0 / DIMN;
  const int hcol = gcol0 - sect * DIMN;
  const int head = hcol >> 6;
  const int row0 = m0 + wr * 64;

  if (sect < 2) {
    const float* bias = sect ? bk : bq;
    const float* lw = sect ? lkw : lqw;
    const float* lb = sect ? lkb : lqb;
    bf16* dst = sect ? kbf : qb;
    const float oscale = sect ? 1.f : QSCALE;
    float bb[4], lww[4], lbb[4];
#pragma unroll
    for (int n = 0; n < 4; ++n) {
      const int d = (n << 4) + clo;
      bb[n] = bias[hcol + d];
      lww[n] = lw[d];
      lbb[n] = lb[d];
    }
#pragma unroll
    for (int m = 0; m < 4; ++m) {
#pragma unroll
      for (int r = 0; r < 4; ++r) {
        const int row = row0 + m * 16 + lhi * 4 + r;
        float x[4];
#pragma unroll
        for (int n = 0; n < 4; ++n) x[n] = acc[m][n][r] + bb[n];
        float s_ = (x[0] + x[1]) + (x[2] + x[3]);
        float q_ = x[0] * x[0];
        q_ = fmaf(x[1], x[1], q_);
        q_ = fmaf(x[2], x[2], q_);
        q_ = fmaf(x[3], x[3], q_);
#pragma unroll
        for (int off = 1; off <= 8; off <<= 1) {
          s_ += __shfl_xor(s_, off);
          q_ += __shfl_xor(q_, off);
        }
        const float mu = s_ * (1.f / 64.f);
        const float var = q_ * (1.f / 64.f) - mu * mu;
        const float rst = rsqrtf(var + 1e-5f);
        float xn[4];
#pragma unroll
        for (int n = 0; n < 4; ++n) xn[n] = (x[n] - mu) * rst * lww[n] + lbb[n];
        const bool dorope = (row >= TTXT) && (row < S_TOT);
        if (dorope) {
          const float* cr = cosT + (long)(row - TTXT) * HD;
          const float* sr2 = sinT + (long)(row - TTXT) * HD;
#pragma unroll
          for (int n = 0; n < 4; ++n) {
            const int d = (n << 4) + clo;
            const float p = __shfl_xor(xn[n], 1);
            xn[n] = xn[n] * cr[d] + ((clo & 1) ? p : -p) * sr2[d];
          }
        }
#pragma unroll
        for (int n = 0; n < 4; ++n)
          dst[((long)head * S_PAD + row) * HD + (n << 4) + clo] =
              __float2bfloat16(xn[n] * oscale);
      }
    }
  } else {
    float bb[4];
#pragma unroll
    for (int n = 0; n < 4; ++n) bb[n] = bv[hcol + (n << 4) + clo];
    bf16* Lp = reinterpret_cast<bf16*>(smem + w * 9216);
#pragma unroll
    for (int m = 0; m < 4; ++m)
#pragma unroll
      for (int n = 0; n < 4; ++n)
#pragma unroll
        for (int r = 0; r < 4; ++r)
          Lp[((n << 4) + clo) * 72 + m * 16 + lhi * 4 + r] =
              __float2bfloat16(acc[m][n][r] + bb[n]);
    const int dsub = lane >> 3, sc = lane & 7;
#pragma unroll
    for (int it = 0; it < 8; ++it) {
      const int d = it * 8 + dsub;
      s16x8 v = *reinterpret_cast<const s16x8*>(&Lp[d * 72 + sc * 8]);
      *reinterpret_cast<s16x8*>(vt + ((long)head * HD + d) * S_PAD + row0 + sc * 8) = v;
    }
  }
}

// ==== proj GEMM v9 (unchanged): 128x64 tile, 4 waves, BK=32, tri-buffer 36KB ====
__global__ __launch_bounds__(256, 4) void k_gemm_proj9(const bf16* __restrict__ A,
                                                       const bf16* __restrict__ B,
                                                       float* __restrict__ C,
                                                       const float* __restrict__ bias) {
  __shared__ __align__(16) char smem[3 * 12288];
  const int tid = threadIdx.x;
  const int w = tid >> 6, lane = tid & 63;
  const int clo = lane & 15, lhi = lane >> 4;
  const int wr = w >> 1, wc = w & 1;
  const int m0 = blockIdx.y * 128, n0 = blockIdx.x * 64;

  const int u1 = 256 + tid;
  const long ga0 = (long)(m0 + (tid >> 2)) * DIMN + (((tid & 3) ^ ((tid >> 2) & 3)) * 8);
  const long ga1 = (long)(m0 + (u1 >> 2)) * DIMN + (((u1 & 3) ^ ((u1 >> 2) & 3)) * 8);
  const long gb0 = (long)(n0 + (tid >> 2)) * DIMN + (((tid & 3) ^ ((tid >> 2) & 3)) * 8);
  const int wbase = w * 1024;

  auto stage = [&](int b, int kt) {
    char* Ab = &smem[b * 12288];
    char* Bb = Ab + 8192;
    const int ko = kt * 32;
    GLOAD_LDS16(A + ga0 + ko, Ab + wbase);
    GLOAD_LDS16(A + ga1 + ko, Ab + 4096 + wbase);
    GLOAD_LDS16(B + gb0 + ko, Bb + wbase);
  };

  auto rdf = [&](const char* base, int row) {
    return *reinterpret_cast<const s16x8*>(base + row * 64 + ((lhi ^ (row & 3)) * 16));
  };

  f32x4 acc[4][2] = {};

  stage(0, 0);
  stage(1, 1);
  for (int t = 0; t < NKT32; ++t) {
    if (t < NKT32 - 1)
      asm volatile("s_waitcnt vmcnt(3)" ::: "memory");
    else
      asm volatile("s_waitcnt vmcnt(0)" ::: "memory");
    __builtin_amdgcn_s_barrier();
    if (t + 2 < NKT32) stage((t + 2) % 3, t + 2);
    const char* Ab = &smem[(t % 3) * 12288];
    const char* Bb = Ab + 8192;
    s16x8 af[4], bfr[2];
#pragma unroll
    for (int m = 0; m < 4; ++m) af[m] = rdf(Ab, wr * 64 + m * 16 + clo);
#pragma unroll
    for (int n = 0; n < 2; ++n) bfr[n] = rdf(Bb, wc * 32 + n * 16 + clo);
    __builtin_amdgcn_s_setprio(1);
#pragma unroll
    for (int m = 0; m < 4; ++m)
#pragma unroll
      for (int n = 0; n < 2; ++n)
        acc[m][n] = __builtin_amdgcn_mfma_f32_16x16x32_bf16(af[m], bfr[n], acc[m][n], 0, 0, 0);
    __builtin_amdgcn_s_setprio(0);
  }
#pragma unroll
  for (int n = 0; n < 2; ++n) {
    const int col = n0 + wc * 32 + n * 16 + clo;
    const float bvv = bias[col];
#pragma unroll
    for (int m = 0; m < 4; ++m) {
#pragma unroll
      for (int r = 0; r < 4; ++r) {
        const int row = m0 + wr * 64 + m * 16 + lhi * 4 + r;
        if (row < S_TOT) {
          const int dst = (row >= TTXT) ? (row - TTXT) : (row + (S_TOT - TTXT));
          C[(long)dst * DIMN + col] = acc[m][n][r] + bvv;
        }
      }
    }
  }
}

// ==== flash v12: static-max softmax, 4 waves/block (128 q-rows), 5 blocks/CU ====
__global__ __launch_bounds__(256, 5) void k_flash12(const bf16* __restrict__ qb,
                                                    const bf16* __restrict__ kbf,
                                                    const bf16* __restrict__ vt,
                                                    float* __restrict__ po,
                                                    float* __restrict__ pl) {
  __shared__ __align__(16) char smem[32768];
  const int h = blockIdx.x, qt = blockIdx.y, ks = blockIdx.z;
  const int tid = threadIdx.x, w = tid >> 6, lane = tid & 63;
  const int l31 = lane & 31, hf = lane >> 5;
  const bf16* Qh = qb + (long)h * S_PAD * HD;
  const bf16* Kh = kbf + (long)h * S_PAD * HD;
  const bf16* Vh = vt + (long)h * HD * S_PAD;
  const int q0w = qt * 128 + w * 32;
  const int T0 = ks * 12;

  s16x8 qf[4];
#pragma unroll
  for (int t = 0; t < 4; ++t)
    qf[t] = *reinterpret_cast<const s16x8*>(Qh + (long)(q0w + l31) * HD + t * 16 + hf * 8);

  f32x16 accO[2] = {};
  f32x16 lacc = {};

  const s16x8 ones8 = {0x3F80, 0x3F80, 0x3F80, 0x3F80, 0x3F80, 0x3F80, 0x3F80, 0x3F80};

  // staging: 256 threads x 2 slots each (tid, tid+256); slot u -> row=u>>3, chunk=u&7
  const int sr = tid >> 3, sc8 = tid & 7;
  const long kg0 = (long)sr * HD + ((sc8 ^ (sr & 7)) * 8);
  const long kg1 = kg0 + (long)32 * HD;  // row+32: (row&7) unchanged
  const long vg0 = (long)sr * S_PAD + ((sc8 ^ (sr & 7)) * 8);
  const long vg1 = vg0 + (long)32 * S_PAD;
  const int ldsb = w * 1024;

  auto stage = [&](int b, int kb0) {
    char* Kb = &smem[b * 16384];
    char* Vb = &smem[b * 16384 + 8192];
    GLOAD_LDS16(Kh + (long)kb0 * HD + kg0, Kb + ldsb);
    GLOAD_LDS16(Kh + (long)kb0 * HD + kg1, Kb + 4096 + ldsb);
    GLOAD_LDS16(Vh + kb0 + vg0, Vb + ldsb);
    GLOAD_LDS16(Vh + kb0 + vg1, Vb + 4096 + ldsb);
  };

  auto ldsrd = [&](const char* base, int row, int c) {
    return *reinterpret_cast<const s16x8*>(base + row * 128 + ((c ^ (row & 7)) * 16));
  };
  auto pk2 = [&](float a, float b) -> unsigned {
    __hip_bfloat162 t = __float22bfloat162_rn(make_float2(a, b));
    return *reinterpret_cast<unsigned*>(&t);
  };

  stage(0, T0 * 64);
  __syncthreads();
  int cur = 0;
  for (int kt = 0; kt < 12; ++kt) {
    const int kb0 = (T0 + kt) * 64;
    if (kt + 1 < 12) stage(cur ^ 1, kb0 + 64);
    const char* Kb = &smem[cur * 16384];
    const char* Vb = &smem[cur * 16384 + 8192];

    f32x16 s0 = {}, s1 = {};
#pragma unroll
    for (int t = 0; t < 4; ++t) {
      s16x8 k0 = ldsrd(Kb, l31, 2 * t + hf);
      s16x8 k1 = ldsrd(Kb, 32 + l31, 2 * t + hf);
      s0 = __builtin_amdgcn_mfma_f32_32x32x16_bf16(k0, qf[t], s0, 0, 0, 0);
      s1 = __builtin_amdgcn_mfma_f32_32x32x16_bf16(k1, qf[t], s1, 0, 0, 0);
    }
    if (kb0 + 64 > S_TOT) {
#pragma unroll
      for (int j = 0; j < 16; ++j) {
        const int key = kb0 + (j & 3) + 8 * (j >> 2) + 4 * hf;
        if (key >= S_TOT) s0[j] = -1e30f;
        if (key + 32 >= S_TOT) s1[j] = -1e30f;
      }
    }
    // static-max softmax: P = exp2(s - SMAX); no cross-lane, no rescale
#pragma unroll
    for (int j = 0; j < 16; ++j) {
      s0[j] = exp2f(s0[j] - SMAX);
      s1[j] = exp2f(s1[j] - SMAX);
    }
    unsigned gw0[8], gw1[8];
#pragma unroll
    for (int i = 0; i < 4; ++i) {
      gw0[2 * i] = pk2(s0[4 * i], s0[4 * i + 1]);
      gw0[2 * i + 1] = pk2(s0[4 * i + 2], s0[4 * i + 3]);
      gw1[2 * i] = pk2(s1[4 * i], s1[4 * i + 1]);
      gw1[2 * i + 1] = pk2(s1[4 * i + 2], s1[4 * i + 3]);
    }
    s16x8 pa[4];
#pragma unroll
    for (int b = 0; b < 2; ++b) {
      unsigned* gw = b ? gw1 : gw0;
#pragma unroll
      for (int t = 0; t < 2; ++t) {
        auto rA = __builtin_amdgcn_permlane32_swap(gw[4 * t + 0], gw[4 * t + 2], false, false);
        auto rB = __builtin_amdgcn_permlane32_swap(gw[4 * t + 1], gw[4 * t + 3], false, false);
        union {
          unsigned u[4];
          s16x8 v;
        } A;
        A.u[0] = rA[0];
        A.u[1] = rB[0];
        A.u[2] = rA[1];
        A.u[3] = rB[1];
        pa[b * 2 + t] = A.v;
      }
    }
#pragma unroll
    for (int t4 = 0; t4 < 4; ++t4) {
      s16x8 v0 = ldsrd(Vb, l31, 2 * t4 + hf);
      s16x8 v1 = ldsrd(Vb, 32 + l31, 2 * t4 + hf);
      accO[0] = __builtin_amdgcn_mfma_f32_32x32x16_bf16(pa[t4], v0, accO[0], 0, 0, 0);
      accO[1] = __builtin_amdgcn_mfma_f32_32x32x16_bf16(pa[t4], v1, accO[1], 0, 0, 0);
      lacc = __builtin_amdgcn_mfma_f32_32x32x16_bf16(pa[t4], ones8, lacc, 0, 0, 0);
    }
    __syncthreads();
    cur ^= 1;
  }
  const long rowbase = ((long)(ks * NH + h)) * S_PAD + q0w;
  if (l31 == 0) {
#pragma unroll
    for (int j = 0; j < 16; ++j) pl[rowbase + (j & 3) + 8 * (j >> 2) + 4 * hf] = lacc[j];
  }
#pragma unroll
  for (int j = 0; j < 16; ++j) {
    const int pat = (j & 3) + 8 * (j >> 2) + 4 * hf;
    float* dst = po + (rowbase + pat) * HD + l31;
    dst[0] = accO[0][j];
    dst[32] = accO[1][j];
  }
}

// ---------------- combine the three KV-slices (shared static max: plain sums) --------
__global__ __launch_bounds__(256) void k_combine3(const float* __restrict__ po,
                                                  const float* __restrict__ pl,
                                                  bf16* __restrict__ ao) {
  const int idx = blockIdx.x * 256 + threadIdx.x;  // covers NH*S_PAD*16
  const int d4 = (idx & 15) * 4;
  const int row = (idx >> 4) % S_PAD;
  const int h = idx / (S_PAD * 16);
  if (row >= S_TOT) return;
  float4 o = make_float4(0.f, 0.f, 0.f, 0.f);
  float l = 0.f;
#pragma unroll
  for (int i = 0; i < NSPLIT; ++i) {
    const long r = ((long)(i * NH + h)) * S_PAD + row;
    const float4 p = *reinterpret_cast<const float4*>(po + r * HD + d4);
    o.x += p.x;
    o.y += p.y;
    o.z += p.z;
    o.w += p.w;
    l += pl[r];
  }
  const float inv = 1.f / l;
  union {
    bf16 b[4];
    short4 s4;
  } ob;
  ob.b[0] = __float2bfloat16(o.x * inv);
  ob.b[1] = __float2bfloat16(o.y * inv);
  ob.b[2] = __float2bfloat16(o.z * inv);
  ob.b[3] = __float2bfloat16(o.w * inv);
  *reinterpret_cast<short4*>(ao + (long)row * DIMN + h * HD + d4) = ob.s4;
}

extern "C" void kernel_launch(void* const* d_in, const int* in_sizes, int n_in, void* d_out,
                              int out_size, void* d_ws, size_t ws_size, hipStream_t stream) {
  const float* hid = (const float*)d_in[0];
  const float* enc = (const float*)d_in[1];
  const float* rc = (const float*)d_in[2];
  const float* rs = (const float*)d_in[3];
  const float* Wq = (const float*)d_in[4];
  const float* bq = (const float*)d_in[5];
  const float* Wk = (const float*)d_in[6];
  const float* bk = (const float*)d_in[7];
  const float* Wv = (const float*)d_in[8];
  const float* bv = (const float*)d_in[9];
  const float* lqw = (const float*)d_in[10];
  const float* lqb = (const float*)d_in[11];
  const float* lkw = (const float*)d_in[12];
  const float* lkb = (const float*)d_in[13];
  const float* Wo = (const float*)d_in[14];
  const float* bo = (const float*)d_in[15];
  float* out = (float*)d_out;

  char* ws = (char*)d_ws;
  size_t off = 0;
  float* po = (float*)(ws + off);
  off += (size_t)NSPLIT * NH * S_PAD * HD * 4;
  bf16* h_bf = (bf16*)(ws + off);  // live only until qkv GEMM; then reused for pl
  off += (size_t)S_PAD * DIMN * 2;
  bf16* wqkv = (bf16*)(ws + off);
  off += (size_t)3 * DIMN * DIMN * 2;
  bf16* wo = (bf16*)(ws + off);
  off += (size_t)DIMN * DIMN * 2;
  bf16* q_bf = (bf16*)(ws + off);
  off += (size_t)NH * S_PAD * HD * 2;
  bf16* k_bf = (bf16*)(ws + off);
  off += (size_t)NH * S_PAD * HD * 2;
  bf16* vt_bf = (bf16*)(ws + off);
  off += (size_t)NH * HD * S_PAD * 2;
  bf16* at_bf = (bf16*)(ws + off);
  off += (size_t)S_PAD * DIMN * 2;

  float* pl = (float*)h_bf;  // aliases h_bf (dead after qkv GEMM; rewritten each call)

  const long PREP_N = ((long)S_PAD * DIMN + 4L * DIMN * DIMN) / 4;
  k_prep_all<<<(int)((PREP_N + 255) / 256), 256, 0, stream>>>(hid, enc, Wq, Wk, Wv, Wo, h_bf,
                                                              wqkv, wo);
  k_gemm_qkv9<<<dim3(NQKV / 128, S_PAD / 256), 512, 0, stream>>>(
      h_bf, wqkv, bq, bk, bv, lqw, lqb, lkw, lkb, rc, rs, q_bf, k_bf, vt_bf);
  k_flash12<<<dim3(NH, S_PAD / 128, NSPLIT), 256, 0, stream>>>(q_bf, k_bf, vt_bf, po, pl);
  k_combine3<<<NH * S_PAD * 16 / 256, 256, 0, stream>>>(po, pl, at_bf);
  k_gemm_proj9<<<dim3(DIMN / 64, S_PAD / 128), 256, 0, stream>>>(at_bf, wo, out, bo);
}

// Round 14
// 222.598 us; speedup vs baseline: 1.1997x; 1.1997x over previous
//
#include <hip/hip_runtime.h>
#include <hip/hip_bf16.h>

typedef __hip_bfloat16 bf16;
using f32x4 = __attribute__((ext_vector_type(4))) float;
using f32x16 = __attribute__((ext_vector_type(16))) float;
using s16x8 = __attribute__((ext_vector_type(8))) short;

#define S_TOT 2274
#define S_PAD 2304
#define TTXT 226
#define DIMN 1920
#define NH 30
#define HD 64
#define NQKV 5760
#define QSCALE 0.1803368801f  // 0.125 * log2(e)
#define NSPLIT 3              // flash KV-split
#define SMAX 20.0f            // static softmax max (log2 domain); |score|<=23.1 hard bound

#define GLOAD_LDS16(g, l)                                                              \
  __builtin_amdgcn_global_load_lds((const __attribute__((address_space(1))) void*)(g), \
                                   (__attribute__((address_space(3))) void*)(l), 16, 0, 0)

// bijective XCD swizzle (m204): nwg blocks, 8 XCDs; q=nwg/8, r=nwg%8
__device__ __forceinline__ int xcd_swz(int orig, int nwg) {
  const int q = nwg >> 3, r = nwg & 7;
  const int xcd = orig & 7, pos = orig >> 3;
  return (xcd < r ? xcd * (q + 1) : r * (q + 1) + (xcd - r) * q) + pos;
}

// ---------------- merged prep: f32 -> bf16 for h, Wqkv, Wo (one launch) ----------------
__global__ void k_prep_all(const float* __restrict__ hid, const float* __restrict__ enc,
                           const float* __restrict__ Wq, const float* __restrict__ Wk,
                           const float* __restrict__ Wv, const float* __restrict__ Wo,
                           bf16* __restrict__ h_bf, bf16* __restrict__ wqkv,
                           bf16* __restrict__ wo_bf) {
  const long T1 = (long)S_PAD * DIMN;
  const long PER = (long)DIMN * DIMN;
  long i4 = ((long)blockIdx.x * blockDim.x + threadIdx.x) * 4;
  if (i4 >= T1 + 4 * PER) return;
  float4 v = make_float4(0.f, 0.f, 0.f, 0.f);
  bf16* dst;
  long di;
  if (i4 < T1) {
    int s = (int)(i4 / DIMN);
    if (s < TTXT)
      v = *reinterpret_cast<const float4*>(enc + i4);
    else if (s < S_TOT)
      v = *reinterpret_cast<const float4*>(hid + i4 - (long)TTXT * DIMN);
    dst = h_bf;
    di = i4;
  } else if (i4 < T1 + 3 * PER) {
    const long j = i4 - T1;
    const float* src = (j < PER) ? (Wq + j) : (j < 2 * PER) ? (Wk + j - PER) : (Wv + j - 2 * PER);
    v = *reinterpret_cast<const float4*>(src);
    dst = wqkv;
    di = j;
  } else {
    const long j = i4 - T1 - 3 * PER;
    v = *reinterpret_cast<const float4*>(Wo + j);
    dst = wo_bf;
    di = j;
  }
  union {
    bf16 b[4];
    short4 s4;
  } o;
  o.b[0] = __float2bfloat16(v.x);
  o.b[1] = __float2bfloat16(v.y);
  o.b[2] = __float2bfloat16(v.z);
  o.b[3] = __float2bfloat16(v.w);
  *reinterpret_cast<short4*>(dst + di) = o.s4;
}

// ==== fused QKV GEMM v10: v9 + bijective XCD swizzle (grid 45x9=405) ====
#define NKT32 60
#define QBUF 24576
__global__ __launch_bounds__(512, 4) void k_gemm_qkv10(
    const bf16* __restrict__ A, const bf16* __restrict__ B, const float* __restrict__ bq,
    const float* __restrict__ bk, const float* __restrict__ bv, const float* __restrict__ lqw,
    const float* __restrict__ lqb, const float* __restrict__ lkw, const float* __restrict__ lkb,
    const float* __restrict__ cosT, const float* __restrict__ sinT, bf16* __restrict__ qb,
    bf16* __restrict__ kbf, bf16* __restrict__ vt) {
  __shared__ __align__(16) char smem[3 * QBUF];
  const int tid = threadIdx.x;
  const int w = tid >> 6, lane = tid & 63;
  const int clo = lane & 15, lhi = lane >> 4;
  const int wr = w >> 1, wc = w & 1;
  const int swz = xcd_swz(blockIdx.y * 45 + blockIdx.x, 405);
  const int m0 = (swz / 45) * 256, n0 = (swz % 45) * 128;

  const int u1 = 512 + tid;
  const long ga0 = (long)(m0 + (tid >> 2)) * DIMN + (((tid & 3) ^ ((tid >> 2) & 3)) * 8);
  const long ga1 = (long)(m0 + (u1 >> 2)) * DIMN + (((u1 & 3) ^ ((u1 >> 2) & 3)) * 8);
  const long gb0 = (long)(n0 + (tid >> 2)) * DIMN + (((tid & 3) ^ ((tid >> 2) & 3)) * 8);
  const int wbase = w * 1024;

  auto stage = [&](int b, int kt) {
    char* Ab = &smem[b * QBUF];
    char* Bb = Ab + 16384;
    const int ko = kt * 32;
    GLOAD_LDS16(A + ga0 + ko, Ab + wbase);
    GLOAD_LDS16(A + ga1 + ko, Ab + 8192 + wbase);
    GLOAD_LDS16(B + gb0 + ko, Bb + wbase);
  };

  auto rdf = [&](const char* base, int row) {
    return *reinterpret_cast<const s16x8*>(base + row * 64 + ((lhi ^ (row & 3)) * 16));
  };

  f32x4 acc[4][4] = {};

  stage(0, 0);
  stage(1, 1);
  for (int t = 0; t < NKT32; ++t) {
    if (t < NKT32 - 1)
      asm volatile("s_waitcnt vmcnt(3)" ::: "memory");
    else
      asm volatile("s_waitcnt vmcnt(0)" ::: "memory");
    __builtin_amdgcn_s_barrier();
    if (t + 2 < NKT32) stage((t + 2) % 3, t + 2);
    const char* Ab = &smem[(t % 3) * QBUF];
    const char* Bb = Ab + 16384;
    s16x8 af[4], bfr[4];
#pragma unroll
    for (int m = 0; m < 4; ++m) af[m] = rdf(Ab, wr * 64 + m * 16 + clo);
#pragma unroll
    for (int n = 0; n < 4; ++n) bfr[n] = rdf(Bb, wc * 64 + n * 16 + clo);
    __builtin_amdgcn_s_setprio(1);
#pragma unroll
    for (int m = 0; m < 4; ++m)
#pragma unroll
      for (int n = 0; n < 4; ++n)
        acc[m][n] = __builtin_amdgcn_mfma_f32_16x16x32_bf16(af[m], bfr[n], acc[m][n], 0, 0, 0);
    __builtin_amdgcn_s_setprio(0);
  }
  __syncthreads();

  const int gcol0 = n0 + wc * 64;
  const int sect = gcol0 / DIMN;
  const int hcol = gcol0 - sect * DIMN;
  const int head = hcol >> 6;
  const int row0 = m0 + wr * 64;

  if (sect < 2) {
    const float* bias = sect ? bk : bq;
    const float* lw = sect ? lkw : lqw;
    const float* lb = sect ? lkb : lqb;
    bf16* dst = sect ? kbf : qb;
    const float oscale = sect ? 1.f : QSCALE;
    float bb[4], lww[4], lbb[4];
#pragma unroll
    for (int n = 0; n < 4; ++n) {
      const int d = (n << 4) + clo;
      bb[n] = bias[hcol + d];
      lww[n] = lw[d];
      lbb[n] = lb[d];
    }
#pragma unroll
    for (int m = 0; m < 4; ++m) {
#pragma unroll
      for (int r = 0; r < 4; ++r) {
        const int row = row0 + m * 16 + lhi * 4 + r;
        float x[4];
#pragma unroll
        for (int n = 0; n < 4; ++n) x[n] = acc[m][n][r] + bb[n];
        float s_ = (x[0] + x[1]) + (x[2] + x[3]);
        float q_ = x[0] * x[0];
        q_ = fmaf(x[1], x[1], q_);
        q_ = fmaf(x[2], x[2], q_);
        q_ = fmaf(x[3], x[3], q_);
#pragma unroll
        for (int off = 1; off <= 8; off <<= 1) {
          s_ += __shfl_xor(s_, off);
          q_ += __shfl_xor(q_, off);
        }
        const float mu = s_ * (1.f / 64.f);
        const float var = q_ * (1.f / 64.f) - mu * mu;
        const float rst = rsqrtf(var + 1e-5f);
        float xn[4];
#pragma unroll
        for (int n = 0; n < 4; ++n) xn[n] = (x[n] - mu) * rst * lww[n] + lbb[n];
        const bool dorope = (row >= TTXT) && (row < S_TOT);
        if (dorope) {
          const float* cr = cosT + (long)(row - TTXT) * HD;
          const float* sr2 = sinT + (long)(row - TTXT) * HD;
#pragma unroll
          for (int n = 0; n < 4; ++n) {
            const int d = (n << 4) + clo;
            const float p = __shfl_xor(xn[n], 1);
            xn[n] = xn[n] * cr[d] + ((clo & 1) ? p : -p) * sr2[d];
          }
        }
#pragma unroll
        for (int n = 0; n < 4; ++n)
          dst[((long)head * S_PAD + row) * HD + (n << 4) + clo] =
              __float2bfloat16(xn[n] * oscale);
      }
    }
  } else {
    float bb[4];
#pragma unroll
    for (int n = 0; n < 4; ++n) bb[n] = bv[hcol + (n << 4) + clo];
    bf16* Lp = reinterpret_cast<bf16*>(smem + w * 9216);
#pragma unroll
    for (int m = 0; m < 4; ++m)
#pragma unroll
      for (int n = 0; n < 4; ++n)
#pragma unroll
        for (int r = 0; r < 4; ++r)
          Lp[((n << 4) + clo) * 72 + m * 16 + lhi * 4 + r] =
              __float2bfloat16(acc[m][n][r] + bb[n]);
    const int dsub = lane >> 3, sc = lane & 7;
#pragma unroll
    for (int it = 0; it < 8; ++it) {
      const int d = it * 8 + dsub;
      s16x8 v = *reinterpret_cast<const s16x8*>(&Lp[d * 72 + sc * 8]);
      *reinterpret_cast<s16x8*>(vt + ((long)head * HD + d) * S_PAD + row0 + sc * 8) = v;
    }
  }
}

// ==== proj GEMM v10: v9 + bijective XCD swizzle (grid 30x18=540) ====
__global__ __launch_bounds__(256, 4) void k_gemm_proj10(const bf16* __restrict__ A,
                                                        const bf16* __restrict__ B,
                                                        float* __restrict__ C,
                                                        const float* __restrict__ bias) {
  __shared__ __align__(16) char smem[3 * 12288];
  const int tid = threadIdx.x;
  const int w = tid >> 6, lane = tid & 63;
  const int clo = lane & 15, lhi = lane >> 4;
  const int wr = w >> 1, wc = w & 1;
  const int swz = xcd_swz(blockIdx.y * 30 + blockIdx.x, 540);
  const int m0 = (swz / 30) * 128, n0 = (swz % 30) * 64;

  const int u1 = 256 + tid;
  const long ga0 = (long)(m0 + (tid >> 2)) * DIMN + (((tid & 3) ^ ((tid >> 2) & 3)) * 8);
  const long ga1 = (long)(m0 + (u1 >> 2)) * DIMN + (((u1 & 3) ^ ((u1 >> 2) & 3)) * 8);
  const long gb0 = (long)(n0 + (tid >> 2)) * DIMN + (((tid & 3) ^ ((tid >> 2) & 3)) * 8);
  const int wbase = w * 1024;

  auto stage = [&](int b, int kt) {
    char* Ab = &smem[b * 12288];
    char* Bb = Ab + 8192;
    const int ko = kt * 32;
    GLOAD_LDS16(A + ga0 + ko, Ab + wbase);
    GLOAD_LDS16(A + ga1 + ko, Ab + 4096 + wbase);
    GLOAD_LDS16(B + gb0 + ko, Bb + wbase);
  };

  auto rdf = [&](const char* base, int row) {
    return *reinterpret_cast<const s16x8*>(base + row * 64 + ((lhi ^ (row & 3)) * 16));
  };

  f32x4 acc[4][2] = {};

  stage(0, 0);
  stage(1, 1);
  for (int t = 0; t < NKT32; ++t) {
    if (t < NKT32 - 1)
      asm volatile("s_waitcnt vmcnt(3)" ::: "memory");
    else
      asm volatile("s_waitcnt vmcnt(0)" ::: "memory");
    __builtin_amdgcn_s_barrier();
    if (t + 2 < NKT32) stage((t + 2) % 3, t + 2);
    const char* Ab = &smem[(t % 3) * 12288];
    const char* Bb = Ab + 8192;
    s16x8 af[4], bfr[2];
#pragma unroll
    for (int m = 0; m < 4; ++m) af[m] = rdf(Ab, wr * 64 + m * 16 + clo);
#pragma unroll
    for (int n = 0; n < 2; ++n) bfr[n] = rdf(Bb, wc * 32 + n * 16 + clo);
    __builtin_amdgcn_s_setprio(1);
#pragma unroll
    for (int m = 0; m < 4; ++m)
#pragma unroll
      for (int n = 0; n < 2; ++n)
        acc[m][n] = __builtin_amdgcn_mfma_f32_16x16x32_bf16(af[m], bfr[n], acc[m][n], 0, 0, 0);
    __builtin_amdgcn_s_setprio(0);
  }
#pragma unroll
  for (int n = 0; n < 2; ++n) {
    const int col = n0 + wc * 32 + n * 16 + clo;
    const float bvv = bias[col];
#pragma unroll
    for (int m = 0; m < 4; ++m) {
#pragma unroll
      for (int r = 0; r < 4; ++r) {
        const int row = m0 + wr * 64 + m * 16 + lhi * 4 + r;
        if (row < S_TOT) {
          const int dst = (row >= TTXT) ? (row - TTXT) : (row + (S_TOT - TTXT));
          C[(long)dst * DIMN + col] = acc[m][n][r] + bvv;
        }
      }
    }
  }
}

// ==== flash v13: flash11 (8 waves, static-max) with VALU row-sum (no lacc AGPRs) ====
__global__ __launch_bounds__(512, 4) void k_flash13(const bf16* __restrict__ qb,
                                                    const bf16* __restrict__ kbf,
                                                    const bf16* __restrict__ vt,
                                                    float* __restrict__ po,
                                                    float* __restrict__ pl) {
  __shared__ __align__(16) char smem[32768];
  const int h = blockIdx.x, qt = blockIdx.y, ks = blockIdx.z;
  const int tid = threadIdx.x, w = tid >> 6, lane = tid & 63;
  const int l31 = lane & 31, hf = lane >> 5;
  const bf16* Qh = qb + (long)h * S_PAD * HD;
  const bf16* Kh = kbf + (long)h * S_PAD * HD;
  const bf16* Vh = vt + (long)h * HD * S_PAD;
  const int q0w = qt * 256 + w * 32;
  const int T0 = ks * 12;

  s16x8 qf[4];
#pragma unroll
  for (int t = 0; t < 4; ++t)
    qf[t] = *reinterpret_cast<const s16x8*>(Qh + (long)(q0w + l31) * HD + t * 16 + hf * 8);

  f32x16 accO[2] = {};
  float l_run = 0.f;  // row-sum for q-row l31 (scalar, replaces 16-AGPR lacc)

  const int sr = tid >> 3, sc8 = tid & 7;
  const long kg0 = (long)sr * HD + ((sc8 ^ (sr & 7)) * 8);
  const long vg0 = (long)sr * S_PAD + ((sc8 ^ (sr & 7)) * 8);
  const int ldsb = w * 1024;

  auto stage = [&](int b, int kb0) {
    char* Kb = &smem[b * 16384];
    char* Vb = &smem[b * 16384 + 8192];
    GLOAD_LDS16(Kh + (long)kb0 * HD + kg0, Kb + ldsb);
    GLOAD_LDS16(Vh + kb0 + vg0, Vb + ldsb);
  };

  auto ldsrd = [&](const char* base, int row, int c) {
    return *reinterpret_cast<const s16x8*>(base + row * 128 + ((c ^ (row & 7)) * 16));
  };
  auto pk2 = [&](float a, float b) -> unsigned {
    __hip_bfloat162 t = __float22bfloat162_rn(make_float2(a, b));
    return *reinterpret_cast<unsigned*>(&t);
  };

  stage(0, T0 * 64);
  __syncthreads();
  int cur = 0;
  for (int kt = 0; kt < 12; ++kt) {
    const int kb0 = (T0 + kt) * 64;
    if (kt + 1 < 12) stage(cur ^ 1, kb0 + 64);
    const char* Kb = &smem[cur * 16384];
    const char* Vb = &smem[cur * 16384 + 8192];

    f32x16 s0 = {}, s1 = {};
#pragma unroll
    for (int t = 0; t < 4; ++t) {
      s16x8 k0 = ldsrd(Kb, l31, 2 * t + hf);
      s16x8 k1 = ldsrd(Kb, 32 + l31, 2 * t + hf);
      s0 = __builtin_amdgcn_mfma_f32_32x32x16_bf16(k0, qf[t], s0, 0, 0, 0);
      s1 = __builtin_amdgcn_mfma_f32_32x32x16_bf16(k1, qf[t], s1, 0, 0, 0);
    }
    if (kb0 + 64 > S_TOT) {
#pragma unroll
      for (int j = 0; j < 16; ++j) {
        const int key = kb0 + (j & 3) + 8 * (j >> 2) + 4 * hf;
        if (key >= S_TOT) s0[j] = -1e30f;
        if (key + 32 >= S_TOT) s1[j] = -1e30f;
      }
    }
    // static-max softmax: P = exp2(s - SMAX); masked keys -> exp2(-inf) = 0
#pragma unroll
    for (int j = 0; j < 16; ++j) {
      s0[j] = exp2f(s0[j] - SMAX);
      s1[j] = exp2f(s1[j] - SMAX);
    }
    // row-sum via VALU tree + partner fold (q-row l31 is lane-local)
    {
      float ts[16];
#pragma unroll
      for (int j = 0; j < 16; ++j) ts[j] = s0[j] + s1[j];
#pragma unroll
      for (int st = 8; st >= 1; st >>= 1)
#pragma unroll
        for (int i = 0; i < st; ++i) ts[i] += ts[i + st];
      auto r = __builtin_amdgcn_permlane32_swap(__float_as_uint(ts[0]), __float_as_uint(ts[0]),
                                                false, false);
      l_run += __uint_as_float(r[0]) + __uint_as_float(r[1]);
    }
    unsigned gw0[8], gw1[8];
#pragma unroll
    for (int i = 0; i < 4; ++i) {
      gw0[2 * i] = pk2(s0[4 * i], s0[4 * i + 1]);
      gw0[2 * i + 1] = pk2(s0[4 * i + 2], s0[4 * i + 3]);
      gw1[2 * i] = pk2(s1[4 * i], s1[4 * i + 1]);
      gw1[2 * i + 1] = pk2(s1[4 * i + 2], s1[4 * i + 3]);
    }
    s16x8 pa[4];
#pragma unroll
    for (int b = 0; b < 2; ++b) {
      unsigned* gw = b ? gw1 : gw0;
#pragma unroll
      for (int t = 0; t < 2; ++t) {
        auto rA = __builtin_amdgcn_permlane32_swap(gw[4 * t + 0], gw[4 * t + 2], false, false);
        auto rB = __builtin_amdgcn_permlane32_swap(gw[4 * t + 1], gw[4 * t + 3], false, false);
        union {
          unsigned u[4];
          s16x8 v;
        } A;
        A.u[0] = rA[0];
        A.u[1] = rB[0];
        A.u[2] = rA[1];
        A.u[3] = rB[1];
        pa[b * 2 + t] = A.v;
      }
    }
#pragma unroll
    for (int t4 = 0; t4 < 4; ++t4) {
      s16x8 v0 = ldsrd(Vb, l31, 2 * t4 + hf);
      s16x8 v1 = ldsrd(Vb, 32 + l31, 2 * t4 + hf);
      accO[0] = __builtin_amdgcn_mfma_f32_32x32x16_bf16(pa[t4], v0, accO[0], 0, 0, 0);
      accO[1] = __builtin_amdgcn_mfma_f32_32x32x16_bf16(pa[t4], v1, accO[1], 0, 0, 0);
    }
    __syncthreads();
    cur ^= 1;
  }
  const long rowbase = ((long)(ks * NH + h)) * S_PAD + q0w;
  if (hf == 0) pl[rowbase + l31] = l_run;
#pragma unroll
  for (int j = 0; j < 16; ++j) {
    const int pat = (j & 3) + 8 * (j >> 2) + 4 * hf;
    float* dst = po + (rowbase + pat) * HD + l31;
    dst[0] = accO[0][j];
    dst[32] = accO[1][j];
  }
}

// ---------------- combine the three KV-slices (shared static max: plain sums) --------
__global__ __launch_bounds__(256) void k_combine3(const float* __restrict__ po,
                                                  const float* __restrict__ pl,
                                                  bf16* __restrict__ ao) {
  const int idx = blockIdx.x * 256 + threadIdx.x;  // covers NH*S_PAD*16
  const int d4 = (idx & 15) * 4;
  const int row = (idx >> 4) % S_PAD;
  const int h = idx / (S_PAD * 16);
  if (row >= S_TOT) return;
  float4 o = make_float4(0.f, 0.f, 0.f, 0.f);
  float l = 0.f;
#pragma unroll
  for (int i = 0; i < NSPLIT; ++i) {
    const long r = ((long)(i * NH + h)) * S_PAD + row;
    const float4 p = *reinterpret_cast<const float4*>(po + r * HD + d4);
    o.x += p.x;
    o.y += p.y;
    o.z += p.z;
    o.w += p.w;
    l += pl[r];
  }
  const float inv = 1.f / l;
  union {
    bf16 b[4];
    short4 s4;
  } ob;
  ob.b[0] = __float2bfloat16(o.x * inv);
  ob.b[1] = __float2bfloat16(o.y * inv);
  ob.b[2] = __float2bfloat16(o.z * inv);
  ob.b[3] = __float2bfloat16(o.w * inv);
  *reinterpret_cast<short4*>(ao + (long)row * DIMN + h * HD + d4) = ob.s4;
}

extern "C" void kernel_launch(void* const* d_in, const int* in_sizes, int n_in, void* d_out,
                              int out_size, void* d_ws, size_t ws_size, hipStream_t stream) {
  const float* hid = (const float*)d_in[0];
  const float* enc = (const float*)d_in[1];
  const float* rc = (const float*)d_in[2];
  const float* rs = (const float*)d_in[3];
  const float* Wq = (const float*)d_in[4];
  const float* bq = (const float*)d_in[5];
  const float* Wk = (const float*)d_in[6];
  const float* bk = (const float*)d_in[7];
  const float* Wv = (const float*)d_in[8];
  const float* bv = (const float*)d_in[9];
  const float* lqw = (const float*)d_in[10];
  const float* lqb = (const float*)d_in[11];
  const float* lkw = (const float*)d_in[12];
  const float* lkb = (const float*)d_in[13];
  const float* Wo = (const float*)d_in[14];
  const float* bo = (const float*)d_in[15];
  float* out = (float*)d_out;

  char* ws = (char*)d_ws;
  size_t off = 0;
  float* po = (float*)(ws + off);
  off += (size_t)NSPLIT * NH * S_PAD * HD * 4;
  bf16* h_bf = (bf16*)(ws + off);  // live only until qkv GEMM; then reused for pl
  off += (size_t)S_PAD * DIMN * 2;
  bf16* wqkv = (bf16*)(ws + off);
  off += (size_t)3 * DIMN * DIMN * 2;
  bf16* wo = (bf16*)(ws + off);
  off += (size_t)DIMN * DIMN * 2;
  bf16* q_bf = (bf16*)(ws + off);
  off += (size_t)NH * S_PAD * HD * 2;
  bf16* k_bf = (bf16*)(ws + off);
  off += (size_t)NH * S_PAD * HD * 2;
  bf16* vt_bf = (bf16*)(ws + off);
  off += (size_t)NH * HD * S_PAD * 2;
  bf16* at_bf = (bf16*)(ws + off);
  off += (size_t)S_PAD * DIMN * 2;

  float* pl = (float*)h_bf;  // aliases h_bf (dead after qkv GEMM; rewritten each call)

  const long PREP_N = ((long)S_PAD * DIMN + 4L * DIMN * DIMN) / 4;
  k_prep_all<<<(int)((PREP_N + 255) / 256), 256, 0, stream>>>(hid, enc, Wq, Wk, Wv, Wo, h_bf,
                                                              wqkv, wo);
  k_gemm_qkv10<<<dim3(45, 9), 512, 0, stream>>>(h_bf, wqkv, bq, bk, bv, lqw, lqb, lkw, lkb, rc,
                                                rs, q_bf, k_bf, vt_bf);
  k_flash13<<<dim3(NH, S_PAD / 256, NSPLIT), 512, 0, stream>>>(q_bf, k_bf, vt_bf, po, pl);
  k_combine3<<<NH * S_PAD * 16 / 256, 256, 0, stream>>>(po, pl, at_bf);
  k_gemm_proj10<<<dim3(30, 18), 256, 0, stream>>>(at_bf, wo, out, bo);
}

// Round 15
// 213.079 us; speedup vs baseline: 1.2533x; 1.0447x over previous
//
#include <hip/hip_runtime.h>
#include <hip/hip_bf16.h>

typedef __hip_bfloat16 bf16;
using f32x4 = __attribute__((ext_vector_type(4))) float;
using f32x16 = __attribute__((ext_vector_type(16))) float;
using s16x8 = __attribute__((ext_vector_type(8))) short;

#define S_TOT 2274
#define S_PAD 2304
#define TTXT 226
#define DIMN 1920
#define NH 30
#define HD 64
#define NQKV 5760
#define QSCALE 0.1803368801f  // 0.125 * log2(e)
#define NSPLIT 4              // flash KV-split (36 tiles / 4 = 9 per block)
#define SMAX 20.0f            // static softmax max (log2 domain); |score|<=23.1 hard bound

#define GLOAD_LDS16(g, l)                                                              \
  __builtin_amdgcn_global_load_lds((const __attribute__((address_space(1))) void*)(g), \
                                   (__attribute__((address_space(3))) void*)(l), 16, 0, 0)

// bijective XCD swizzle (m204)
__device__ __forceinline__ int xcd_swz(int orig, int nwg) {
  const int q = nwg >> 3, r = nwg & 7;
  const int xcd = orig & 7, pos = orig >> 3;
  return (xcd < r ? xcd * (q + 1) : r * (q + 1) + (xcd - r) * q) + pos;
}

// ---------------- merged prep: f32 -> bf16 for h, Wqkv, Wo (one launch) ----------------
__global__ void k_prep_all(const float* __restrict__ hid, const float* __restrict__ enc,
                           const float* __restrict__ Wq, const float* __restrict__ Wk,
                           const float* __restrict__ Wv, const float* __restrict__ Wo,
                           bf16* __restrict__ h_bf, bf16* __restrict__ wqkv,
                           bf16* __restrict__ wo_bf) {
  const long T1 = (long)S_PAD * DIMN;
  const long PER = (long)DIMN * DIMN;
  long i4 = ((long)blockIdx.x * blockDim.x + threadIdx.x) * 4;
  if (i4 >= T1 + 4 * PER) return;
  float4 v = make_float4(0.f, 0.f, 0.f, 0.f);
  bf16* dst;
  long di;
  if (i4 < T1) {
    int s = (int)(i4 / DIMN);
    if (s < TTXT)
      v = *reinterpret_cast<const float4*>(enc + i4);
    else if (s < S_TOT)
      v = *reinterpret_cast<const float4*>(hid + i4 - (long)TTXT * DIMN);
    dst = h_bf;
    di = i4;
  } else if (i4 < T1 + 3 * PER) {
    const long j = i4 - T1;
    const float* src = (j < PER) ? (Wq + j) : (j < 2 * PER) ? (Wk + j - PER) : (Wv + j - 2 * PER);
    v = *reinterpret_cast<const float4*>(src);
    dst = wqkv;
    di = j;
  } else {
    const long j = i4 - T1 - 3 * PER;
    v = *reinterpret_cast<const float4*>(Wo + j);
    dst = wo_bf;
    di = j;
  }
  union {
    bf16 b[4];
    short4 s4;
  } o;
  o.b[0] = __float2bfloat16(v.x);
  o.b[1] = __float2bfloat16(v.y);
  o.b[2] = __float2bfloat16(v.z);
  o.b[3] = __float2bfloat16(v.w);
  *reinterpret_cast<short4*>(dst + di) = o.s4;
}

// ==== fused QKV GEMM v11: v10 + conflict-free LDS swizzle (slot ^= (row>>1)&3) ====
#define NKT32 60
#define QBUF 24576
__global__ __launch_bounds__(512, 4) void k_gemm_qkv11(
    const bf16* __restrict__ A, const bf16* __restrict__ B, const float* __restrict__ bq,
    const float* __restrict__ bk, const float* __restrict__ bv, const float* __restrict__ lqw,
    const float* __restrict__ lqb, const float* __restrict__ lkw, const float* __restrict__ lkb,
    const float* __restrict__ cosT, const float* __restrict__ sinT, bf16* __restrict__ qb,
    bf16* __restrict__ kbf, bf16* __restrict__ vt) {
  __shared__ __align__(16) char smem[3 * QBUF];
  const int tid = threadIdx.x;
  const int w = tid >> 6, lane = tid & 63;
  const int clo = lane & 15, lhi = lane >> 4;
  const int wr = w >> 1, wc = w & 1;
  const int swz = xcd_swz(blockIdx.y * 45 + blockIdx.x, 405);
  const int m0 = (swz / 45) * 256, n0 = (swz % 45) * 128;

  // slot u -> row=u>>2, LDS slot u&3 holds global chunk (u&3)^((u>>3)&3)
  const int u1 = 512 + tid;
  const long ga0 = (long)(m0 + (tid >> 2)) * DIMN + (((tid & 3) ^ ((tid >> 3) & 3)) * 8);
  const long ga1 = (long)(m0 + (u1 >> 2)) * DIMN + (((u1 & 3) ^ ((u1 >> 3) & 3)) * 8);
  const long gb0 = (long)(n0 + (tid >> 2)) * DIMN + (((tid & 3) ^ ((tid >> 3) & 3)) * 8);
  const int wbase = w * 1024;

  auto stage = [&](int b, int kt) {
    char* Ab = &smem[b * QBUF];
    char* Bb = Ab + 16384;
    const int ko = kt * 32;
    GLOAD_LDS16(A + ga0 + ko, Ab + wbase);
    GLOAD_LDS16(A + ga1 + ko, Ab + 8192 + wbase);
    GLOAD_LDS16(B + gb0 + ko, Bb + wbase);
  };

  auto rdf = [&](const char* base, int row) {
    return *reinterpret_cast<const s16x8*>(base + row * 64 + ((lhi ^ ((row >> 1) & 3)) * 16));
  };

  f32x4 acc[4][4] = {};

  stage(0, 0);
  stage(1, 1);
  for (int t = 0; t < NKT32; ++t) {
    if (t < NKT32 - 1)
      asm volatile("s_waitcnt vmcnt(3)" ::: "memory");
    else
      asm volatile("s_waitcnt vmcnt(0)" ::: "memory");
    __builtin_amdgcn_s_barrier();
    if (t + 2 < NKT32) stage((t + 2) % 3, t + 2);
    const char* Ab = &smem[(t % 3) * QBUF];
    const char* Bb = Ab + 16384;
    s16x8 af[4], bfr[4];
#pragma unroll
    for (int m = 0; m < 4; ++m) af[m] = rdf(Ab, wr * 64 + m * 16 + clo);
#pragma unroll
    for (int n = 0; n < 4; ++n) bfr[n] = rdf(Bb, wc * 64 + n * 16 + clo);
    __builtin_amdgcn_s_setprio(1);
#pragma unroll
    for (int m = 0; m < 4; ++m)
#pragma unroll
      for (int n = 0; n < 4; ++n)
        acc[m][n] = __builtin_amdgcn_mfma_f32_16x16x32_bf16(af[m], bfr[n], acc[m][n], 0, 0, 0);
    __builtin_amdgcn_s_setprio(0);
  }
  __syncthreads();

  const int gcol0 = n0 + wc * 64;
  const int sect = gcol0 / DIMN;
  const int hcol = gcol0 - sect * DIMN;
  const int head = hcol >> 6;
  const int row0 = m0 + wr * 64;

  if (sect < 2) {
    const float* bias = sect ? bk : bq;
    const float* lw = sect ? lkw : lqw;
    const float* lb = sect ? lkb : lqb;
    bf16* dst = sect ? kbf : qb;
    const float oscale = sect ? 1.f : QSCALE;
    float bb[4], lww[4], lbb[4];
#pragma unroll
    for (int n = 0; n < 4; ++n) {
      const int d = (n << 4) + clo;
      bb[n] = bias[hcol + d];
      lww[n] = lw[d];
      lbb[n] = lb[d];
    }
#pragma unroll
    for (int m = 0; m < 4; ++m) {
#pragma unroll
      for (int r = 0; r < 4; ++r) {
        const int row = row0 + m * 16 + lhi * 4 + r;
        float x[4];
#pragma unroll
        for (int n = 0; n < 4; ++n) x[n] = acc[m][n][r] + bb[n];
        float s_ = (x[0] + x[1]) + (x[2] + x[3]);
        float q_ = x[0] * x[0];
        q_ = fmaf(x[1], x[1], q_);
        q_ = fmaf(x[2], x[2], q_);
        q_ = fmaf(x[3], x[3], q_);
#pragma unroll
        for (int off = 1; off <= 8; off <<= 1) {
          s_ += __shfl_xor(s_, off);
          q_ += __shfl_xor(q_, off);
        }
        const float mu = s_ * (1.f / 64.f);
        const float var = q_ * (1.f / 64.f) - mu * mu;
        const float rst = rsqrtf(var + 1e-5f);
        float xn[4];
#pragma unroll
        for (int n = 0; n < 4; ++n) xn[n] = (x[n] - mu) * rst * lww[n] + lbb[n];
        const bool dorope = (row >= TTXT) && (row < S_TOT);
        if (dorope) {
          const float* cr = cosT + (long)(row - TTXT) * HD;
          const float* sr2 = sinT + (long)(row - TTXT) * HD;
#pragma unroll
          for (int n = 0; n < 4; ++n) {
            const int d = (n << 4) + clo;
            const float p = __shfl_xor(xn[n], 1);
            xn[n] = xn[n] * cr[d] + ((clo & 1) ? p : -p) * sr2[d];
          }
        }
#pragma unroll
        for (int n = 0; n < 4; ++n)
          dst[((long)head * S_PAD + row) * HD + (n << 4) + clo] =
              __float2bfloat16(xn[n] * oscale);
      }
    }
  } else {
    float bb[4];
#pragma unroll
    for (int n = 0; n < 4; ++n) bb[n] = bv[hcol + (n << 4) + clo];
    bf16* Lp = reinterpret_cast<bf16*>(smem + w * 9216);
#pragma unroll
    for (int m = 0; m < 4; ++m)
#pragma unroll
      for (int n = 0; n < 4; ++n)
#pragma unroll
        for (int r = 0; r < 4; ++r)
          Lp[((n << 4) + clo) * 72 + m * 16 + lhi * 4 + r] =
              __float2bfloat16(acc[m][n][r] + bb[n]);
    const int dsub = lane >> 3, sc = lane & 7;
#pragma unroll
    for (int it = 0; it < 8; ++it) {
      const int d = it * 8 + dsub;
      s16x8 v = *reinterpret_cast<const s16x8*>(&Lp[d * 72 + sc * 8]);
      *reinterpret_cast<s16x8*>(vt + ((long)head * HD + d) * S_PAD + row0 + sc * 8) = v;
    }
  }
}

// ==== proj GEMM v11: conflict-free swizzle variant ====
__global__ __launch_bounds__(256, 4) void k_gemm_proj11(const bf16* __restrict__ A,
                                                        const bf16* __restrict__ B,
                                                        float* __restrict__ C,
                                                        const float* __restrict__ bias) {
  __shared__ __align__(16) char smem[3 * 12288];
  const int tid = threadIdx.x;
  const int w = tid >> 6, lane = tid & 63;
  const int clo = lane & 15, lhi = lane >> 4;
  const int wr = w >> 1, wc = w & 1;
  const int swz = xcd_swz(blockIdx.y * 30 + blockIdx.x, 540);
  const int m0 = (swz / 30) * 128, n0 = (swz % 30) * 64;

  const int u1 = 256 + tid;
  const long ga0 = (long)(m0 + (tid >> 2)) * DIMN + (((tid & 3) ^ ((tid >> 3) & 3)) * 8);
  const long ga1 = (long)(m0 + (u1 >> 2)) * DIMN + (((u1 & 3) ^ ((u1 >> 3) & 3)) * 8);
  const long gb0 = (long)(n0 + (tid >> 2)) * DIMN + (((tid & 3) ^ ((tid >> 3) & 3)) * 8);
  const int wbase = w * 1024;

  auto stage = [&](int b, int kt) {
    char* Ab = &smem[b * 12288];
    char* Bb = Ab + 8192;
    const int ko = kt * 32;
    GLOAD_LDS16(A + ga0 + ko, Ab + wbase);
    GLOAD_LDS16(A + ga1 + ko, Ab + 4096 + wbase);
    GLOAD_LDS16(B + gb0 + ko, Bb + wbase);
  };

  auto rdf = [&](const char* base, int row) {
    return *reinterpret_cast<const s16x8*>(base + row * 64 + ((lhi ^ ((row >> 1) & 3)) * 16));
  };

  f32x4 acc[4][2] = {};

  stage(0, 0);
  stage(1, 1);
  for (int t = 0; t < NKT32; ++t) {
    if (t < NKT32 - 1)
      asm volatile("s_waitcnt vmcnt(3)" ::: "memory");
    else
      asm volatile("s_waitcnt vmcnt(0)" ::: "memory");
    __builtin_amdgcn_s_barrier();
    if (t + 2 < NKT32) stage((t + 2) % 3, t + 2);
    const char* Ab = &smem[(t % 3) * 12288];
    const char* Bb = Ab + 8192;
    s16x8 af[4], bfr[2];
#pragma unroll
    for (int m = 0; m < 4; ++m) af[m] = rdf(Ab, wr * 64 + m * 16 + clo);
#pragma unroll
    for (int n = 0; n < 2; ++n) bfr[n] = rdf(Bb, wc * 32 + n * 16 + clo);
    __builtin_amdgcn_s_setprio(1);
#pragma unroll
    for (int m = 0; m < 4; ++m)
#pragma unroll
      for (int n = 0; n < 2; ++n)
        acc[m][n] = __builtin_amdgcn_mfma_f32_16x16x32_bf16(af[m], bfr[n], acc[m][n], 0, 0, 0);
    __builtin_amdgcn_s_setprio(0);
  }
#pragma unroll
  for (int n = 0; n < 2; ++n) {
    const int col = n0 + wc * 32 + n * 16 + clo;
    const float bvv = bias[col];
#pragma unroll
    for (int m = 0; m < 4; ++m) {
#pragma unroll
      for (int r = 0; r < 4; ++r) {
        const int row = m0 + wr * 64 + m * 16 + lhi * 4 + r;
        if (row < S_TOT) {
          const int dst = (row >= TTXT) ? (row - TTXT) : (row + (S_TOT - TTXT));
          C[(long)dst * DIMN + col] = acc[m][n][r] + bvv;
        }
      }
    }
  }
}

// ==== flash v14: flash11 structure (8 waves, static-max, lacc-MFMA rowsum),
// ==== NSPLIT=4 (9 tiles/block, 1080 blocks), bf16 partials ====
__global__ __launch_bounds__(512, 4) void k_flash14(const bf16* __restrict__ qb,
                                                    const bf16* __restrict__ kbf,
                                                    const bf16* __restrict__ vt,
                                                    bf16* __restrict__ po,
                                                    float* __restrict__ pl) {
  __shared__ __align__(16) char smem[32768];
  const int h = blockIdx.x, qt = blockIdx.y, ks = blockIdx.z;
  const int tid = threadIdx.x, w = tid >> 6, lane = tid & 63;
  const int l31 = lane & 31, hf = lane >> 5;
  const bf16* Qh = qb + (long)h * S_PAD * HD;
  const bf16* Kh = kbf + (long)h * S_PAD * HD;
  const bf16* Vh = vt + (long)h * HD * S_PAD;
  const int q0w = qt * 256 + w * 32;
  const int T0 = ks * 9;

  s16x8 qf[4];
#pragma unroll
  for (int t = 0; t < 4; ++t)
    qf[t] = *reinterpret_cast<const s16x8*>(Qh + (long)(q0w + l31) * HD + t * 16 + hf * 8);

  f32x16 accO[2] = {};
  f32x16 lacc = {};

  const s16x8 ones8 = {0x3F80, 0x3F80, 0x3F80, 0x3F80, 0x3F80, 0x3F80, 0x3F80, 0x3F80};

  const int sr = tid >> 3, sc8 = tid & 7;
  const long kg0 = (long)sr * HD + ((sc8 ^ (sr & 7)) * 8);
  const long vg0 = (long)sr * S_PAD + ((sc8 ^ (sr & 7)) * 8);
  const int ldsb = w * 1024;

  auto stage = [&](int b, int kb0) {
    char* Kb = &smem[b * 16384];
    char* Vb = &smem[b * 16384 + 8192];
    GLOAD_LDS16(Kh + (long)kb0 * HD + kg0, Kb + ldsb);
    GLOAD_LDS16(Vh + kb0 + vg0, Vb + ldsb);
  };

  auto ldsrd = [&](const char* base, int row, int c) {
    return *reinterpret_cast<const s16x8*>(base + row * 128 + ((c ^ (row & 7)) * 16));
  };
  auto pk2 = [&](float a, float b) -> unsigned {
    __hip_bfloat162 t = __float22bfloat162_rn(make_float2(a, b));
    return *reinterpret_cast<unsigned*>(&t);
  };

  stage(0, T0 * 64);
  __syncthreads();
  int cur = 0;
  for (int kt = 0; kt < 9; ++kt) {
    const int kb0 = (T0 + kt) * 64;
    if (kt + 1 < 9) stage(cur ^ 1, kb0 + 64);
    const char* Kb = &smem[cur * 16384];
    const char* Vb = &smem[cur * 16384 + 8192];

    f32x16 s0 = {}, s1 = {};
#pragma unroll
    for (int t = 0; t < 4; ++t) {
      s16x8 k0 = ldsrd(Kb, l31, 2 * t + hf);
      s16x8 k1 = ldsrd(Kb, 32 + l31, 2 * t + hf);
      s0 = __builtin_amdgcn_mfma_f32_32x32x16_bf16(k0, qf[t], s0, 0, 0, 0);
      s1 = __builtin_amdgcn_mfma_f32_32x32x16_bf16(k1, qf[t], s1, 0, 0, 0);
    }
    if (kb0 + 64 > S_TOT) {
#pragma unroll
      for (int j = 0; j < 16; ++j) {
        const int key = kb0 + (j & 3) + 8 * (j >> 2) + 4 * hf;
        if (key >= S_TOT) s0[j] = -1e30f;
        if (key + 32 >= S_TOT) s1[j] = -1e30f;
      }
    }
    // static-max softmax: P = exp2(s - SMAX)
#pragma unroll
    for (int j = 0; j < 16; ++j) {
      s0[j] = exp2f(s0[j] - SMAX);
      s1[j] = exp2f(s1[j] - SMAX);
    }
    unsigned gw0[8], gw1[8];
#pragma unroll
    for (int i = 0; i < 4; ++i) {
      gw0[2 * i] = pk2(s0[4 * i], s0[4 * i + 1]);
      gw0[2 * i + 1] = pk2(s0[4 * i + 2], s0[4 * i + 3]);
      gw1[2 * i] = pk2(s1[4 * i], s1[4 * i + 1]);
      gw1[2 * i + 1] = pk2(s1[4 * i + 2], s1[4 * i + 3]);
    }
    s16x8 pa[4];
#pragma unroll
    for (int b = 0; b < 2; ++b) {
      unsigned* gw = b ? gw1 : gw0;
#pragma unroll
      for (int t = 0; t < 2; ++t) {
        auto rA = __builtin_amdgcn_permlane32_swap(gw[4 * t + 0], gw[4 * t + 2], false, false);
        auto rB = __builtin_amdgcn_permlane32_swap(gw[4 * t + 1], gw[4 * t + 3], false, false);
        union {
          unsigned u[4];
          s16x8 v;
        } A;
        A.u[0] = rA[0];
        A.u[1] = rB[0];
        A.u[2] = rA[1];
        A.u[3] = rB[1];
        pa[b * 2 + t] = A.v;
      }
    }
#pragma unroll
    for (int t4 = 0; t4 < 4; ++t4) {
      s16x8 v0 = ldsrd(Vb, l31, 2 * t4 + hf);
      s16x8 v1 = ldsrd(Vb, 32 + l31, 2 * t4 + hf);
      accO[0] = __builtin_amdgcn_mfma_f32_32x32x16_bf16(pa[t4], v0, accO[0], 0, 0, 0);
      accO[1] = __builtin_amdgcn_mfma_f32_32x32x16_bf16(pa[t4], v1, accO[1], 0, 0, 0);
      lacc = __builtin_amdgcn_mfma_f32_32x32x16_bf16(pa[t4], ones8, lacc, 0, 0, 0);
    }
    __syncthreads();
    cur ^= 1;
  }
  const long rowbase = ((long)(ks * NH + h)) * S_PAD + q0w;
  if (l31 == 0) {
#pragma unroll
    for (int j = 0; j < 16; ++j) pl[rowbase + (j & 3) + 8 * (j >> 2) + 4 * hf] = lacc[j];
  }
#pragma unroll
  for (int j = 0; j < 16; ++j) {
    const int pat = (j & 3) + 8 * (j >> 2) + 4 * hf;
    bf16* dst = po + (rowbase + pat) * HD + l31;
    dst[0] = __float2bfloat16(accO[0][j]);
    dst[32] = __float2bfloat16(accO[1][j]);
  }
}

// ---------------- combine the four KV-slices (bf16 partials, plain sums) --------
__global__ __launch_bounds__(256) void k_combine4(const bf16* __restrict__ po,
                                                  const float* __restrict__ pl,
                                                  bf16* __restrict__ ao) {
  const int idx = blockIdx.x * 256 + threadIdx.x;  // covers NH*S_PAD*16
  const int d4 = (idx & 15) * 4;
  const int row = (idx >> 4) % S_PAD;
  const int h = idx / (S_PAD * 16);
  if (row >= S_TOT) return;
  float o[4] = {0.f, 0.f, 0.f, 0.f};
  float l = 0.f;
#pragma unroll
  for (int i = 0; i < NSPLIT; ++i) {
    const long r = ((long)(i * NH + h)) * S_PAD + row;
    const ushort4 p = *reinterpret_cast<const ushort4*>(po + r * HD + d4);
    o[0] += __uint_as_float((unsigned)p.x << 16);
    o[1] += __uint_as_float((unsigned)p.y << 16);
    o[2] += __uint_as_float((unsigned)p.z << 16);
    o[3] += __uint_as_float((unsigned)p.w << 16);
    l += pl[r];
  }
  const float inv = 1.f / l;
  union {
    bf16 b[4];
    short4 s4;
  } ob;
#pragma unroll
  for (int i = 0; i < 4; ++i) ob.b[i] = __float2bfloat16(o[i] * inv);
  *reinterpret_cast<short4*>(ao + (long)row * DIMN + h * HD + d4) = ob.s4;
}

extern "C" void kernel_launch(void* const* d_in, const int* in_sizes, int n_in, void* d_out,
                              int out_size, void* d_ws, size_t ws_size, hipStream_t stream) {
  const float* hid = (const float*)d_in[0];
  const float* enc = (const float*)d_in[1];
  const float* rc = (const float*)d_in[2];
  const float* rs = (const float*)d_in[3];
  const float* Wq = (const float*)d_in[4];
  const float* bq = (const float*)d_in[5];
  const float* Wk = (const float*)d_in[6];
  const float* bk = (const float*)d_in[7];
  const float* Wv = (const float*)d_in[8];
  const float* bv = (const float*)d_in[9];
  const float* lqw = (const float*)d_in[10];
  const float* lqb = (const float*)d_in[11];
  const float* lkw = (const float*)d_in[12];
  const float* lkb = (const float*)d_in[13];
  const float* Wo = (const float*)d_in[14];
  const float* bo = (const float*)d_in[15];
  float* out = (float*)d_out;

  char* ws = (char*)d_ws;
  size_t off = 0;
  bf16* po = (bf16*)(ws + off);  // NSPLIT*NH*S_PAD*HD*2 = 35.4 MB, within 53.08 MB slot
  off += (size_t)S_PAD * NQKV * 4;
  bf16* h_bf = (bf16*)(ws + off);  // live only until qkv GEMM; then reused for pl
  off += (size_t)S_PAD * DIMN * 2;
  bf16* wqkv = (bf16*)(ws + off);
  off += (size_t)3 * DIMN * DIMN * 2;
  bf16* wo = (bf16*)(ws + off);
  off += (size_t)DIMN * DIMN * 2;
  bf16* q_bf = (bf16*)(ws + off);
  off += (size_t)NH * S_PAD * HD * 2;
  bf16* k_bf = (bf16*)(ws + off);
  off += (size_t)NH * S_PAD * HD * 2;
  bf16* vt_bf = (bf16*)(ws + off);
  off += (size_t)NH * HD * S_PAD * 2;
  bf16* at_bf = (bf16*)(ws + off);
  off += (size_t)S_PAD * DIMN * 2;

  float* pl = (float*)h_bf;  // NSPLIT*NH*S_PAD*4 = 1.1 MB, aliases dead h_bf

  const long PREP_N = ((long)S_PAD * DIMN + 4L * DIMN * DIMN) / 4;
  k_prep_all<<<(int)((PREP_N + 255) / 256), 256, 0, stream>>>(hid, enc, Wq, Wk, Wv, Wo, h_bf,
                                                              wqkv, wo);
  k_gemm_qkv11<<<dim3(45, 9), 512, 0, stream>>>(h_bf, wqkv, bq, bk, bv, lqw, lqb, lkw, lkb, rc,
                                                rs, q_bf, k_bf, vt_bf);
  k_flash14<<<dim3(NH, S_PAD / 256, NSPLIT), 512, 0, stream>>>(q_bf, k_bf, vt_bf, po, pl);
  k_combine4<<<NH * S_PAD * 16 / 256, 256, 0, stream>>>(po, pl, at_bf);
  k_gemm_proj11<<<dim3(30, 18), 256, 0, stream>>>(at_bf, wo, out, bo);
}